// Round 2
// baseline (127.318 us; speedup 1.0000x reference)
//
#include <hip/hip_runtime.h>
#include <math.h>

// Tropical (max-plus) matmul: y[b,o] = max_i (x[b,i] + W[o,i])
// x: [512,1024] f32, W: [1024,1024] f32 (K-innermost), y: [512,1024] f32.
//
// LDS-read-bound kernel (no MFMA path for max-plus). This version:
//  - 128x128 tile, TM=TN=8 per thread (256 thr): LDS bytes/op = 4(TM+TN)/(TM*TN)
//    = 1 B/op (was 2 B/op at 4x4) -> halves LDS pipe time.
//  - k-pair-interleaved LDS layout As[kp][2m+e]: feeds v_pk_add_f32 + v_max3_f32
//    (1 VALU inst per element-k).
//  - conflict-free fragment reads: A = 4 unique addrs/wave (2-way, free);
//    B = fragmented column ownership (n = 2tx+32jj) so each ds_read_b128 is
//    16 consecutive 16B chunks across lanes (2-way, free).
//  - all ds_read offsets are compile-time immediates off one base VGPR.
//  - double-buffered LDS (64 KB), one barrier per K-tile, loads issued early.
// Split-K: 32 tiles x KS slices -> partial max in ws, then reduce. Exact.

#define MDIM 512
#define NDIM 1024
#define KDIM 1024

#define BM 128
#define BN 128
#define BK 32
#define KPR 16          // BK/2 k-pair rows per tile
#define STR 256         // floats per pair-row = 2*BM (1024 B, 16B aligned)
#define TM 8
#define TN 8
#define NTHREADS 256

typedef float v2f __attribute__((ext_vector_type(2)));

__global__ __launch_bounds__(NTHREADS, 1)
void tropical_partial(const float* __restrict__ x, const float* __restrict__ W,
                      float* __restrict__ ws, int KC) {
    __shared__ float As[2][KPR][STR];   // As[buf][kp][2*m + e], e = k&1
    __shared__ float Bs[2][KPR][STR];

    const int tiles_n = NDIM / BN;                  // 8
    const int tm0 = (blockIdx.x / tiles_n) * BM;
    const int tn0 = (blockIdx.x % tiles_n) * BM;    // BM==BN
    const int k0  = blockIdx.y * KC;

    const int tid = threadIdx.x;
    // staging map: 2 threads per row, 16 consecutive k each
    const int sm = tid >> 1;                        // 0..127
    const int sk = (tid & 1) * 16;                  // 0 or 16
    const int sp = sk >> 1;                         // pair base 0 or 8
    // compute map
    const int tx = tid & 15;                        // n-direction
    const int ty = tid >> 4;                        // m-direction (0..15)

    float acc[TM][TN];
#pragma unroll
    for (int i = 0; i < TM; ++i)
#pragma unroll
        for (int j = 0; j < TN; ++j) acc[i][j] = -INFINITY;

    const float* xrow = x + (size_t)(tm0 + sm) * KDIM + sk;
    const float* wrow = W + (size_t)(tn0 + sm) * KDIM + sk;

    float4 a[4], b[4];
    // prologue: load tile 0
    {
        const float4* xp = (const float4*)(xrow + k0);
        const float4* wp = (const float4*)(wrow + k0);
        a[0] = xp[0]; a[1] = xp[1]; a[2] = xp[2]; a[3] = xp[3];
        b[0] = wp[0]; b[1] = wp[1]; b[2] = wp[2]; b[3] = wp[3];
    }
    // write tile 0 into buf 0 (pair-interleaved, 16x ds_write_b64)
#define WRITE_TILE(bf)                                              \
    {                                                               \
        _Pragma("unroll")                                           \
        for (int q = 0; q < 4; ++q) {                               \
            v2f lo, hi;                                             \
            lo.x = a[q].x; lo.y = a[q].y;                           \
            hi.x = a[q].z; hi.y = a[q].w;                           \
            *(v2f*)&As[bf][sp + 2 * q + 0][2 * sm] = lo;            \
            *(v2f*)&As[bf][sp + 2 * q + 1][2 * sm] = hi;            \
            lo.x = b[q].x; lo.y = b[q].y;                           \
            hi.x = b[q].z; hi.y = b[q].w;                           \
            *(v2f*)&Bs[bf][sp + 2 * q + 0][2 * sm] = lo;            \
            *(v2f*)&Bs[bf][sp + 2 * q + 1][2 * sm] = hi;            \
        }                                                           \
    }
    WRITE_TILE(0)

    const int nt = KC / BK;
    for (int t = 0; t < nt; ++t) {
        const int cur = t & 1;
        // issue next tile's global loads early (latency hides under compute)
        if (t + 1 < nt) {
            const float4* xp = (const float4*)(xrow + k0 + (t + 1) * BK);
            const float4* wp = (const float4*)(wrow + k0 + (t + 1) * BK);
            a[0] = xp[0]; a[1] = xp[1]; a[2] = xp[2]; a[3] = xp[3];
            b[0] = wp[0]; b[1] = wp[1]; b[2] = wp[2]; b[3] = wp[3];
        }
        __syncthreads();   // buf[cur] writes visible; prev reads of buf[cur^1] done

        // compute from buf[cur]
        const float4* Ap = ((const float4*)As[cur]) + ty * 4;  // rows ty*8..ty*8+7
        const float4* Bp = ((const float4*)Bs[cur]) + tx;      // cols 2tx+32jj(+1)
#pragma unroll
        for (int kp = 0; kp < KPR; ++kp) {
            const float4 af0 = Ap[kp * 64 + 0];
            const float4 af1 = Ap[kp * 64 + 1];
            const float4 af2 = Ap[kp * 64 + 2];
            const float4 af3 = Ap[kp * 64 + 3];
            const float4 bf0 = Bp[kp * 64 + 0];
            const float4 bf1 = Bp[kp * 64 + 16];
            const float4 bf2 = Bp[kp * 64 + 32];
            const float4 bf3 = Bp[kp * 64 + 48];
            v2f am[TM], bn[TN];
            am[0].x = af0.x; am[0].y = af0.y;  am[1].x = af0.z; am[1].y = af0.w;
            am[2].x = af1.x; am[2].y = af1.y;  am[3].x = af1.z; am[3].y = af1.w;
            am[4].x = af2.x; am[4].y = af2.y;  am[5].x = af2.z; am[5].y = af2.w;
            am[6].x = af3.x; am[6].y = af3.y;  am[7].x = af3.z; am[7].y = af3.w;
            bn[0].x = bf0.x; bn[0].y = bf0.y;  bn[1].x = bf0.z; bn[1].y = bf0.w;
            bn[2].x = bf1.x; bn[2].y = bf1.y;  bn[3].x = bf1.z; bn[3].y = bf1.w;
            bn[4].x = bf2.x; bn[4].y = bf2.y;  bn[5].x = bf2.z; bn[5].y = bf2.w;
            bn[6].x = bf3.x; bn[6].y = bf3.y;  bn[7].x = bf3.z; bn[7].y = bf3.w;
#pragma unroll
            for (int i = 0; i < TM; ++i)
#pragma unroll
                for (int j = 0; j < TN; ++j) {
                    const v2f s = am[i] + bn[j];                   // v_pk_add_f32
                    acc[i][j] = fmaxf(fmaxf(acc[i][j], s.x), s.y); // v_max3_f32
                }
        }

        // write next tile into the other buffer (safe: it was last read at t-1,
        // and every wave passed this iteration's barrier after those reads)
        if (t + 1 < nt) {
            const int nxt = cur ^ 1;
            WRITE_TILE(nxt)
        }
    }

    // epilogue: thread owns rows ty*8+i, cols 2tx + 32jj + (0,1)
    float* wsl = ws + (size_t)blockIdx.y * (MDIM * NDIM);
#pragma unroll
    for (int i = 0; i < TM; ++i) {
        float* r = &wsl[(size_t)(tm0 + ty * TM + i) * NDIM + tn0 + 2 * tx];
#pragma unroll
        for (int jj = 0; jj < 4; ++jj) {
            v2f v;
            v.x = acc[i][2 * jj];
            v.y = acc[i][2 * jj + 1];
            *(v2f*)(r + 32 * jj) = v;
        }
    }
#undef WRITE_TILE
}

__global__ __launch_bounds__(NTHREADS)
void tropical_reduce(const float* __restrict__ ws, float* __restrict__ out, int KS) {
    const int i = blockIdx.x * NTHREADS + threadIdx.x;       // float4 index
    const int stride = MDIM * NDIM / 4;
    if (i >= stride) return;
    const float4* w4 = (const float4*)ws;
    float4 m = w4[i];
    for (int s = 1; s < KS; ++s) {
        const float4 v = w4[(size_t)s * stride + i];
        m.x = fmaxf(m.x, v.x); m.y = fmaxf(m.y, v.y);
        m.z = fmaxf(m.z, v.z); m.w = fmaxf(m.w, v.w);
    }
    ((float4*)out)[i] = m;
}

extern "C" void kernel_launch(void* const* d_in, const int* in_sizes, int n_in,
                              void* d_out, int out_size, void* d_ws, size_t ws_size,
                              hipStream_t stream) {
    const float* x = (const float*)d_in[0];
    const float* W = (const float*)d_in[1];
    float* out = (float*)d_out;
    float* ws  = (float*)d_ws;

    const size_t slice = (size_t)MDIM * NDIM * sizeof(float);  // 2 MB per K-slice
    int KS = 8;
    while (KS > 1 && (size_t)KS * slice > ws_size) KS >>= 1;

    const int ntiles = (MDIM / BM) * (NDIM / BN);  // 32

    if ((size_t)KS * slice > ws_size) {
        // tiny-workspace fallback: single slice straight into out, no reduce
        tropical_partial<<<dim3(ntiles, 1), NTHREADS, 0, stream>>>(x, W, out, KDIM);
        return;
    }

    const int KC = KDIM / KS;
    tropical_partial<<<dim3(ntiles, KS), NTHREADS, 0, stream>>>(x, W, ws, KC);

    const int nvec4 = MDIM * NDIM / 4;
    tropical_reduce<<<(nvec4 + NTHREADS - 1) / NTHREADS, NTHREADS, 0, stream>>>(ws, out, KS);
}

// Round 4
// 91.315 us; speedup vs baseline: 1.3943x; 1.3943x over previous
//
#include <hip/hip_runtime.h>
#include <math.h>

// Tropical (max-plus) matmul: y[b,o] = max_i (x[b,i] + W[o,i])
// x: [512,1024] f32, W: [1024,1024] f32 (K-innermost), y: [512,1024] f32.
//
// Round-4 == Round-3 resubmit (round-3 bench died to a container-acquisition
// failure, not a kernel verdict; static re-audit found no OOB/hang hazard).
//
// Structure: ONE WAVE per 64x64 output tile, TM=TN=8 per lane.
//  - LDS bytes/op = 1 B/op (the round-2 win) but at 64-thr blocks: VGPR-heavy
//    acc stays legal at 2 waves/SIMD, and KS=16 gives 2048 blocks = 8 waves/CU
//    (round-2 failure was 1 wave/SIMD -> latency-exposed, VALUBusy 20%).
//  - No __syncthreads anywhere: block == wave, LDS is wave-private,
//    ordering is plain program order (per-wave DS ops retire in order).
//  - k-pair-interleaved LDS (feeds v_pk_add_f32 + v_max3_f32 = 1 inst/elem-k)
//    with chunk swizzle p = c ^ (c>>2) and 33-chunk (528 B) row stride:
//    fragment reads bank-conflict-free, staging writes ~2-way (free).
//  - Next K-tile global loads issued into registers before compute (T14).
// Split-K: 128 tiles x KS=16 slices -> partial max in ws (32 MB), then reduce.

#define MDIM 512
#define NDIM 1024
#define KDIM 1024

#define TILE 64
#define BK 32
#define KPR (BK / 2)     // 16 k-pair rows per LDS tile
#define CH 33            // 32 data chunks (16 B) + 1 pad chunk per row
#define ROWF (CH * 4)    // 132 floats per kp-row (528 B, 16B-aligned)
#define NTHREADS 64

typedef float v2f __attribute__((ext_vector_type(2)));

__device__ __forceinline__ int swz(int c) { return c ^ (c >> 2); }

__global__ __launch_bounds__(NTHREADS, 2)
void tropical_partial(const float* __restrict__ x, const float* __restrict__ W,
                      float* __restrict__ ws, int KC) {
    __shared__ float As[KPR * ROWF];   // 8448 B
    __shared__ float Bs[KPR * ROWF];   // 8448 B

    const int tiles_n = NDIM / TILE;                // 16
    const int tm0 = (blockIdx.x / tiles_n) * TILE;
    const int tn0 = (blockIdx.x % tiles_n) * TILE;
    const int k0  = blockIdx.y * KC;

    const int l  = threadIdx.x;        // 0..63 (one wave)
    const int q  = l & 7;              // staging: k-offset/4  | compute: tx
    const int r0 = l >> 3;             // staging: row base    | compute: ty
    const int tx = q, ty = r0;

    float acc[8][8];
#pragma unroll
    for (int i = 0; i < 8; ++i)
#pragma unroll
        for (int j = 0; j < 8; ++j) acc[i][j] = -INFINITY;

    // staging bases: lane covers rows r0+8j, k-bytes [4q..4q+3] of each tile
    const float* xb = x + (size_t)tm0 * KDIM + k0 + 4 * q;
    const float* wb = W + (size_t)tn0 * KDIM + k0 + 4 * q;

    float4 xg[8], wg[8];
    const int nt = KC / BK;

    // prologue: load tile 0 (8 rows x 16 B per lane per array; lanes 0..7 cover
    // one dense 128 B row-segment -> 8x128 B transactions per load batch)
#pragma unroll
    for (int j = 0; j < 8; ++j) {
        xg[j] = *(const float4*)(xb + (size_t)(r0 + 8 * j) * KDIM);
        wg[j] = *(const float4*)(wb + (size_t)(r0 + 8 * j) * KDIM);
    }

    for (int t = 0; t < nt; ++t) {
        // regs -> LDS, pair-interleaved + swizzled.
        // float4 covers k-pairs (4q,4q+1)->row 2q and (4q+2,4q+3)->row 2q+1.
#pragma unroll
        for (int j = 0; j < 8; ++j) {
            const int ms  = r0 + 8 * j;                    // m within tile
            const int col = swz(ms >> 1) * 4 + (ms & 1) * 2;
            v2f lo, hi;
            lo.x = xg[j].x; lo.y = xg[j].y;
            hi.x = xg[j].z; hi.y = xg[j].w;
            *(v2f*)&As[(2 * q) * ROWF + col]     = lo;
            *(v2f*)&As[(2 * q + 1) * ROWF + col] = hi;
            lo.x = wg[j].x; lo.y = wg[j].y;
            hi.x = wg[j].z; hi.y = wg[j].w;
            *(v2f*)&Bs[(2 * q) * ROWF + col]     = lo;
            *(v2f*)&Bs[(2 * q + 1) * ROWF + col] = hi;
        }
        // issue next tile's global loads now; in flight during compute below.
        // (ds_write reads regs at issue, so redefining xg/wg here is safe.)
        if (t + 1 < nt) {
            const float* xn = xb + (size_t)(t + 1) * BK;
            const float* wn = wb + (size_t)(t + 1) * BK;
#pragma unroll
            for (int j = 0; j < 8; ++j) {
                xg[j] = *(const float4*)(xn + (size_t)(r0 + 8 * j) * KDIM);
                wg[j] = *(const float4*)(wn + (size_t)(r0 + 8 * j) * KDIM);
            }
        }
        // compute tile t: per kp-row, 4+4 conflict-free ds_read_b128,
        // then 64x (v_pk_add_f32 + v_max3_f32).
#pragma unroll
        for (int kp = 0; kp < KPR; ++kp) {
            const float* ra = As + kp * ROWF;
            const float* rb = Bs + kp * ROWF;
            float4 af[4], bf[4];
#pragma unroll
            for (int qq = 0; qq < 4; ++qq) {
                af[qq] = *(const float4*)(ra + ((4 * ty + qq) ^ ty) * 4);
                bf[qq] = *(const float4*)(rb + ((4 * tx + qq) ^ tx) * 4);
            }
            v2f am[8], bn[8];
#pragma unroll
            for (int qq = 0; qq < 4; ++qq) {
                am[2 * qq].x     = af[qq].x; am[2 * qq].y     = af[qq].y;
                am[2 * qq + 1].x = af[qq].z; am[2 * qq + 1].y = af[qq].w;
                bn[2 * qq].x     = bf[qq].x; bn[2 * qq].y     = bf[qq].y;
                bn[2 * qq + 1].x = bf[qq].z; bn[2 * qq + 1].y = bf[qq].w;
            }
#pragma unroll
            for (int i = 0; i < 8; ++i)
#pragma unroll
                for (int j = 0; j < 8; ++j) {
                    const v2f s = am[i] + bn[j];                    // v_pk_add_f32
                    acc[i][j] = fmaxf(fmaxf(acc[i][j], s.x), s.y);  // v_max3_f32
                }
        }
    }

    // epilogue: lane owns rows tm0+8ty+i, cols tn0+8tx..+7
    float* wsl = ws + (size_t)blockIdx.y * (MDIM * NDIM);
#pragma unroll
    for (int i = 0; i < 8; ++i) {
        float* r = &wsl[(size_t)(tm0 + 8 * ty + i) * NDIM + tn0 + 8 * tx];
        *(float4*)(r)     = make_float4(acc[i][0], acc[i][1], acc[i][2], acc[i][3]);
        *(float4*)(r + 4) = make_float4(acc[i][4], acc[i][5], acc[i][6], acc[i][7]);
    }
}

__global__ __launch_bounds__(256)
void tropical_reduce(const float* __restrict__ ws, float* __restrict__ out, int KS) {
    const int i = blockIdx.x * 256 + threadIdx.x;        // float4 index (exact grid)
    const int stride = MDIM * NDIM / 4;
    const float4* w4 = (const float4*)ws;
    float4 m = w4[i];
#pragma unroll 4
    for (int s = 1; s < KS; ++s) {
        const float4 v = w4[(size_t)s * stride + i];
        m.x = fmaxf(m.x, v.x); m.y = fmaxf(m.y, v.y);
        m.z = fmaxf(m.z, v.z); m.w = fmaxf(m.w, v.w);
    }
    ((float4*)out)[i] = m;
}

extern "C" void kernel_launch(void* const* d_in, const int* in_sizes, int n_in,
                              void* d_out, int out_size, void* d_ws, size_t ws_size,
                              hipStream_t stream) {
    const float* x = (const float*)d_in[0];
    const float* W = (const float*)d_in[1];
    float* out = (float*)d_out;
    float* ws  = (float*)d_ws;

    const size_t slice = (size_t)MDIM * NDIM * sizeof(float);  // 2 MB per K-slice
    int KS = 16;                                   // 2048 blocks = 8 waves/CU
    while (KS > 1 && (size_t)KS * slice > ws_size) KS >>= 1;

    const int ntiles = (MDIM / TILE) * (NDIM / TILE);  // 128

    if (slice > ws_size) {
        // tiny-workspace fallback: single slice straight into out, no reduce
        tropical_partial<<<dim3(ntiles, 1), NTHREADS, 0, stream>>>(x, W, out, KDIM);
        return;
    }

    const int KC = KDIM / KS;
    tropical_partial<<<dim3(ntiles, KS), NTHREADS, 0, stream>>>(x, W, ws, KC);

    const int nvec4 = MDIM * NDIM / 4;                 // 131072
    tropical_reduce<<<nvec4 / 256, 256, 0, stream>>>(ws, out, KS);
}